// Round 1
// baseline (2010.982 us; speedup 1.0000x reference)
//
#include <hip/hip_runtime.h>

#define NN 50000
#define NE 800000

// ---------------------------------------------------------------------------
// cnt[n] = number of edges with row==n (row = edge_index[0])
__global__ __launch_bounds__(256) void count_kernel(const int* __restrict__ row,
                                                    float* __restrict__ cnt) {
  int e = blockIdx.x * 256 + threadIdx.x;
  if (e < NE) atomicAdd(&cnt[row[e]], 1.0f);
}

// W1c[k][j] = We1[k][j] + We1[64+k][j]   (row==col fold), k<64, j<128
__global__ __launch_bounds__(256) void prep_w1c(const float* __restrict__ We1,
                                                float* __restrict__ W1c) {
  int i = blockIdx.x * 256 + threadIdx.x;
  if (i < 64 * 128) W1c[i] = We1[i] + We1[64 * 128 + i];
}

// ---------------------------------------------------------------------------
// P[N,128] = x @ W1c + be1   (per-source-node part of the edge MLP layer 1)
__global__ __launch_bounds__(256) void node_pre(const float* x,
                                                const float* __restrict__ W1c,
                                                const float* __restrict__ be1,
                                                float* __restrict__ P) {
  __shared__ float sA[32][65];     // x tile, padded
  __shared__ float sW[16 * 128];   // weight k-chunk
  const int t = threadIdx.x;
  const int n0 = blockIdx.x * 32;

  for (int i = t; i < 512; i += 256) {   // 32 rows * 16 float4
    int r = i >> 4, c4 = i & 15;
    int n = n0 + r;
    float4 v = make_float4(0.f, 0.f, 0.f, 0.f);
    if (n < NN) v = ((const float4*)(x + (size_t)n * 64))[c4];
    sA[r][c4 * 4 + 0] = v.x; sA[r][c4 * 4 + 1] = v.y;
    sA[r][c4 * 4 + 2] = v.z; sA[r][c4 * 4 + 3] = v.w;
  }

  const int cg = t & 31, rg = t >> 5;
  const int j0 = cg * 4, r0 = rg * 4;
  float acc[4][4] = {};
  for (int kc = 0; kc < 4; ++kc) {
    __syncthreads();
    for (int i = t; i < 512; i += 256)
      ((float4*)sW)[i] = ((const float4*)(W1c + kc * 16 * 128))[i];
    __syncthreads();
    const int kb = kc * 16;
    for (int k = 0; k < 16; ++k) {
      float a0 = sA[r0 + 0][kb + k];
      float a1 = sA[r0 + 1][kb + k];
      float a2 = sA[r0 + 2][kb + k];
      float a3 = sA[r0 + 3][kb + k];
      float4 b = *(const float4*)&sW[k * 128 + j0];
      acc[0][0] += a0 * b.x; acc[0][1] += a0 * b.y; acc[0][2] += a0 * b.z; acc[0][3] += a0 * b.w;
      acc[1][0] += a1 * b.x; acc[1][1] += a1 * b.y; acc[1][2] += a1 * b.z; acc[1][3] += a1 * b.w;
      acc[2][0] += a2 * b.x; acc[2][1] += a2 * b.y; acc[2][2] += a2 * b.z; acc[2][3] += a2 * b.w;
      acc[3][0] += a3 * b.x; acc[3][1] += a3 * b.y; acc[3][2] += a3 * b.z; acc[3][3] += a3 * b.w;
    }
  }
  float4 bias = ((const float4*)be1)[cg];
  for (int i = 0; i < 4; ++i) {
    int n = n0 + r0 + i;
    if (n < NN) {
      float4 o = make_float4(acc[i][0] + bias.x, acc[i][1] + bias.y,
                             acc[i][2] + bias.z, acc[i][3] + bias.w);
      ((float4*)(P + (size_t)n * 128))[cg] = o;
    }
  }
}

// ---------------------------------------------------------------------------
// Per edge e: h = relu(P[row[e]] + ea[e] @ W1f); e_new = h @ We2 + be2;
// ea_out[e] = ea[e] + e_new; agg[row[e]] += e_new (atomic).
__global__ __launch_bounds__(256) void edge_kernel(
    const float* ea_in,              // may alias ea_out (in-place iter 2)
    const float* __restrict__ P,     // [N,128]
    const float* __restrict__ W1f,   // [64,128] = We1 rows 128..191
    const float* __restrict__ We2,   // [128,64]
    const float* __restrict__ be2,   // [64]
    const int* __restrict__ row_idx, // [E]
    float* ea_out,                   // [E,64]
    float* __restrict__ agg) {       // [N,64]
  __shared__ float sA[32][65];       // ea tile
  __shared__ float sH[32][132];      // hidden tile
  __shared__ float sW[16 * 128];     // weight chunk (reused by both GEMMs)
  __shared__ int sRow[32];

  const int t = threadIdx.x;
  const int e0 = blockIdx.x * 32;

  if (t < 32) sRow[t] = row_idx[e0 + t];
  for (int i = t; i < 512; i += 256) {   // 32 rows * 16 float4
    int r = i >> 4, c4 = i & 15;
    float4 v = ((const float4*)(ea_in + (size_t)(e0 + r) * 64))[c4];
    sA[r][c4 * 4 + 0] = v.x; sA[r][c4 * 4 + 1] = v.y;
    sA[r][c4 * 4 + 2] = v.z; sA[r][c4 * 4 + 3] = v.w;
  }

  // GEMM1: [32x64](ea) @ [64x128](W1f)
  const int cg = t & 31, rg = t >> 5;
  const int j0 = cg * 4, r0 = rg * 4;
  float acc1[4][4] = {};
  for (int kc = 0; kc < 4; ++kc) {
    __syncthreads();
    for (int i = t; i < 512; i += 256)
      ((float4*)sW)[i] = ((const float4*)(W1f + kc * 16 * 128))[i];
    __syncthreads();
    const int kb = kc * 16;
    for (int k = 0; k < 16; ++k) {
      float a0 = sA[r0 + 0][kb + k];
      float a1 = sA[r0 + 1][kb + k];
      float a2 = sA[r0 + 2][kb + k];
      float a3 = sA[r0 + 3][kb + k];
      float4 b = *(const float4*)&sW[k * 128 + j0];
      acc1[0][0] += a0 * b.x; acc1[0][1] += a0 * b.y; acc1[0][2] += a0 * b.z; acc1[0][3] += a0 * b.w;
      acc1[1][0] += a1 * b.x; acc1[1][1] += a1 * b.y; acc1[1][2] += a1 * b.z; acc1[1][3] += a1 * b.w;
      acc1[2][0] += a2 * b.x; acc1[2][1] += a2 * b.y; acc1[2][2] += a2 * b.z; acc1[2][3] += a2 * b.w;
      acc1[3][0] += a3 * b.x; acc1[3][1] += a3 * b.y; acc1[3][2] += a3 * b.z; acc1[3][3] += a3 * b.w;
    }
  }
  // h = relu(acc1 + P[row])
  for (int i = 0; i < 4; ++i) {
    float4 p = ((const float4*)(P + (size_t)sRow[r0 + i] * 128))[cg];
    sH[r0 + i][j0 + 0] = fmaxf(acc1[i][0] + p.x, 0.f);
    sH[r0 + i][j0 + 1] = fmaxf(acc1[i][1] + p.y, 0.f);
    sH[r0 + i][j0 + 2] = fmaxf(acc1[i][2] + p.z, 0.f);
    sH[r0 + i][j0 + 3] = fmaxf(acc1[i][3] + p.w, 0.f);
  }

  // GEMM2: [32x128](h) @ [128x64](We2)
  const int cg2 = t & 15, rg2 = t >> 4;
  const int j2 = cg2 * 4, r2 = rg2 * 2;
  float acc2[2][4] = {};
  for (int kc = 0; kc < 4; ++kc) {
    __syncthreads();
    for (int i = t; i < 512; i += 256)
      ((float4*)sW)[i] = ((const float4*)(We2 + kc * 32 * 64))[i];
    __syncthreads();
    const int kb = kc * 32;
    for (int k = 0; k < 32; ++k) {
      float a0 = sH[r2 + 0][kb + k];
      float a1 = sH[r2 + 1][kb + k];
      float4 b = *(const float4*)&sW[k * 64 + j2];
      acc2[0][0] += a0 * b.x; acc2[0][1] += a0 * b.y; acc2[0][2] += a0 * b.z; acc2[0][3] += a0 * b.w;
      acc2[1][0] += a1 * b.x; acc2[1][1] += a1 * b.y; acc2[1][2] += a1 * b.z; acc2[1][3] += a1 * b.w;
    }
  }
  float4 bias = ((const float4*)be2)[cg2];
  for (int i = 0; i < 2; ++i) {
    const int er = r2 + i;
    float v0 = acc2[i][0] + bias.x;
    float v1 = acc2[i][1] + bias.y;
    float v2 = acc2[i][2] + bias.z;
    float v3 = acc2[i][3] + bias.w;
    float4 o = make_float4(sA[er][j2 + 0] + v0, sA[er][j2 + 1] + v1,
                           sA[er][j2 + 2] + v2, sA[er][j2 + 3] + v3);
    ((float4*)(ea_out + (size_t)(e0 + er) * 64))[cg2] = o;
    float* ag = agg + (size_t)sRow[er] * 64 + j2;
    atomicAdd(ag + 0, v0);
    atomicAdd(ag + 1, v1);
    atomicAdd(ag + 2, v2);
    atomicAdd(ag + 3, v3);
  }
}

// ---------------------------------------------------------------------------
// x_out = x + (relu([x | agg/denom] @ Wn1 + bn1) @ Wn2 + bn2)
__global__ __launch_bounds__(256) void node_kernel(
    const float* x,                  // may alias x_out (in-place iter 2)
    const float* __restrict__ agg,   // [N,64]
    const float* __restrict__ cnt,   // [N]
    const float* __restrict__ Wn1,   // [128,128]
    const float* __restrict__ bn1,   // [128]
    const float* __restrict__ Wn2,   // [128,64]
    const float* __restrict__ bn2,   // [64]
    float* x_out) {                  // [N,64]
  __shared__ float sA[32][132];      // [x | agg/denom] tile
  __shared__ float sH[32][132];
  __shared__ float sW[16 * 128];
  const int t = threadIdx.x;
  const int n0 = blockIdx.x * 32;

  for (int i = t; i < 1024; i += 256) {  // 32 rows * 32 float4
    int r = i >> 5, c4 = i & 31;
    int n = n0 + r;
    float4 v = make_float4(0.f, 0.f, 0.f, 0.f);
    if (n < NN) {
      if (c4 < 16) {
        v = ((const float4*)(x + (size_t)n * 64))[c4];
      } else {
        v = ((const float4*)(agg + (size_t)n * 64))[c4 - 16];
        float inv = 1.0f / fmaxf(cnt[n], 1.0f);
        v.x *= inv; v.y *= inv; v.z *= inv; v.w *= inv;
      }
    }
    sA[r][c4 * 4 + 0] = v.x; sA[r][c4 * 4 + 1] = v.y;
    sA[r][c4 * 4 + 2] = v.z; sA[r][c4 * 4 + 3] = v.w;
  }

  // GEMM1: [32x128] @ [128x128](Wn1)
  const int cg = t & 31, rg = t >> 5;
  const int j0 = cg * 4, r0 = rg * 4;
  float acc[4][4] = {};
  for (int kc = 0; kc < 8; ++kc) {
    __syncthreads();
    for (int i = t; i < 512; i += 256)
      ((float4*)sW)[i] = ((const float4*)(Wn1 + kc * 16 * 128))[i];
    __syncthreads();
    const int kb = kc * 16;
    for (int k = 0; k < 16; ++k) {
      float a0 = sA[r0 + 0][kb + k];
      float a1 = sA[r0 + 1][kb + k];
      float a2 = sA[r0 + 2][kb + k];
      float a3 = sA[r0 + 3][kb + k];
      float4 b = *(const float4*)&sW[k * 128 + j0];
      acc[0][0] += a0 * b.x; acc[0][1] += a0 * b.y; acc[0][2] += a0 * b.z; acc[0][3] += a0 * b.w;
      acc[1][0] += a1 * b.x; acc[1][1] += a1 * b.y; acc[1][2] += a1 * b.z; acc[1][3] += a1 * b.w;
      acc[2][0] += a2 * b.x; acc[2][1] += a2 * b.y; acc[2][2] += a2 * b.z; acc[2][3] += a2 * b.w;
      acc[3][0] += a3 * b.x; acc[3][1] += a3 * b.y; acc[3][2] += a3 * b.z; acc[3][3] += a3 * b.w;
    }
  }
  float4 b1 = ((const float4*)bn1)[cg];
  for (int i = 0; i < 4; ++i) {
    sH[r0 + i][j0 + 0] = fmaxf(acc[i][0] + b1.x, 0.f);
    sH[r0 + i][j0 + 1] = fmaxf(acc[i][1] + b1.y, 0.f);
    sH[r0 + i][j0 + 2] = fmaxf(acc[i][2] + b1.z, 0.f);
    sH[r0 + i][j0 + 3] = fmaxf(acc[i][3] + b1.w, 0.f);
  }

  // GEMM2: [32x128](h) @ [128x64](Wn2)
  const int cg2 = t & 15, rg2 = t >> 4;
  const int j2 = cg2 * 4, r2 = rg2 * 2;
  float acc2[2][4] = {};
  for (int kc = 0; kc < 4; ++kc) {
    __syncthreads();
    for (int i = t; i < 512; i += 256)
      ((float4*)sW)[i] = ((const float4*)(Wn2 + kc * 32 * 64))[i];
    __syncthreads();
    const int kb = kc * 32;
    for (int k = 0; k < 32; ++k) {
      float a0 = sH[r2 + 0][kb + k];
      float a1 = sH[r2 + 1][kb + k];
      float4 b = *(const float4*)&sW[k * 64 + j2];
      acc2[0][0] += a0 * b.x; acc2[0][1] += a0 * b.y; acc2[0][2] += a0 * b.z; acc2[0][3] += a0 * b.w;
      acc2[1][0] += a1 * b.x; acc2[1][1] += a1 * b.y; acc2[1][2] += a1 * b.z; acc2[1][3] += a1 * b.w;
    }
  }
  float4 b2 = ((const float4*)bn2)[cg2];
  for (int i = 0; i < 2; ++i) {
    int n = n0 + r2 + i;
    if (n < NN) {
      float4 o;
      o.x = sA[r2 + i][j2 + 0] + acc2[i][0] + b2.x;
      o.y = sA[r2 + i][j2 + 1] + acc2[i][1] + b2.y;
      o.z = sA[r2 + i][j2 + 2] + acc2[i][2] + b2.z;
      o.w = sA[r2 + i][j2 + 3] + acc2[i][3] + b2.w;
      ((float4*)(x_out + (size_t)n * 64))[cg2] = o;
    }
  }
}

// ---------------------------------------------------------------------------
extern "C" void kernel_launch(void* const* d_in, const int* in_sizes, int n_in,
                              void* d_out, int out_size, void* d_ws, size_t ws_size,
                              hipStream_t stream) {
  const float* x   = (const float*)d_in[0];
  const float* ea  = (const float*)d_in[1];
  const float* We1 = (const float*)d_in[2];
  const float* be1 = (const float*)d_in[3];
  const float* We2 = (const float*)d_in[4];
  const float* be2 = (const float*)d_in[5];
  const float* Wn1 = (const float*)d_in[6];
  const float* bn1 = (const float*)d_in[7];
  const float* Wn2 = (const float*)d_in[8];
  const float* bn2 = (const float*)d_in[9];
  const int*   ei  = (const int*)d_in[10];   // row = ei[0..E)

  float* x_out  = (float*)d_out;                       // [N,64]
  float* ea_out = (float*)d_out + (size_t)NN * 64;     // [E,64]

  // workspace layout (floats): cnt[N] | agg[N*64] | P[N*128] | W1c[64*128]
  float* cnt = (float*)d_ws;
  float* agg = cnt + 50048;
  float* P   = agg + (size_t)NN * 64;
  float* W1c = P + (size_t)NN * 128;
  const float* W1f = We1 + 128 * 128;  // rows 128..191 of We1

  hipMemsetAsync(cnt, 0, NN * sizeof(float), stream);
  hipMemsetAsync(agg, 0, (size_t)NN * 64 * sizeof(float), stream);
  count_kernel<<<(NE + 255) / 256, 256, 0, stream>>>(ei, cnt);
  prep_w1c<<<32, 256, 0, stream>>>(We1, W1c);

  const int nbN = (NN + 31) / 32;   // 1563
  const int nbE = NE / 32;          // 25000

  // iter 1
  node_pre<<<nbN, 256, 0, stream>>>(x, W1c, be1, P);
  edge_kernel<<<nbE, 256, 0, stream>>>(ea, P, W1f, We2, be2, ei, ea_out, agg);
  node_kernel<<<nbN, 256, 0, stream>>>(x, agg, cnt, Wn1, bn1, Wn2, bn2, x_out);

  // iter 2 (in-place on d_out)
  hipMemsetAsync(agg, 0, (size_t)NN * 64 * sizeof(float), stream);
  node_pre<<<nbN, 256, 0, stream>>>(x_out, W1c, be1, P);
  edge_kernel<<<nbE, 256, 0, stream>>>(ea_out, P, W1f, We2, be2, ei, ea_out, agg);
  node_kernel<<<nbN, 256, 0, stream>>>(x_out, agg, cnt, Wn1, bn1, Wn2, bn2, x_out);
}

// Round 2
// 1175.989 us; speedup vs baseline: 1.7100x; 1.7100x over previous
//
#include <hip/hip_runtime.h>
#include <hip/hip_bf16.h>

#define NN 50000
#define NE 800000

typedef __attribute__((ext_vector_type(8))) short bf16x8;
typedef __attribute__((ext_vector_type(4))) float f32x4;

__device__ __forceinline__ unsigned short f2bf(float x) {
  __hip_bfloat16 b = __float2bfloat16(x);
  return *reinterpret_cast<unsigned short*>(&b);
}

// ---------------------------------------------------------------------------
__global__ __launch_bounds__(256) void count_kernel(const int* __restrict__ row,
                                                    float* __restrict__ cnt) {
  int e = blockIdx.x * 256 + threadIdx.x;
  if (e < NE) atomicAdd(&cnt[row[e]], 1.0f);
}

// W1c[k][j] = We1[k][j] + We1[64+k][j]   (row==col fold), k<64, j<128
__global__ __launch_bounds__(256) void prep_w1c(const float* __restrict__ We1,
                                                float* __restrict__ W1c) {
  int i = blockIdx.x * 256 + threadIdx.x;
  if (i < 64 * 128) W1c[i] = We1[i] + We1[64 * 128 + i];
}

// Pre-transposed bf16 edge weights:
//  W1fT[n][k] = bf16(We1[128+k][n])  n<128,k<64   (B operand of GEMM1)
//  We2T[n][k] = bf16(We2[k][n])      n<64, k<128  (B operand of GEMM2)
__global__ __launch_bounds__(256) void prep_edge_w(const float* __restrict__ We1,
                                                   const float* __restrict__ We2,
                                                   unsigned short* __restrict__ W1fT,
                                                   unsigned short* __restrict__ We2T) {
  int i = blockIdx.x * 256 + threadIdx.x;
  if (i < 8192) {
    int n = i >> 6, k = i & 63;
    W1fT[i] = f2bf(We1[(128 + k) * 128 + n]);
  } else if (i < 16384) {
    int j = i - 8192;
    int n = j >> 7, k = j & 127;
    We2T[j] = f2bf(We2[k * 64 + n]);
  }
}

// ---------------------------------------------------------------------------
// P[N,128] = x @ W1c + be1   (fp32; per-source-node part of edge MLP layer 1)
__global__ __launch_bounds__(256) void node_pre(const float* x,
                                                const float* __restrict__ W1c,
                                                const float* __restrict__ be1,
                                                float* __restrict__ P) {
  __shared__ float sA[32][65];
  __shared__ float sW[16 * 128];
  const int t = threadIdx.x;
  const int n0 = blockIdx.x * 32;

  for (int i = t; i < 512; i += 256) {
    int r = i >> 4, c4 = i & 15;
    int n = n0 + r;
    float4 v = make_float4(0.f, 0.f, 0.f, 0.f);
    if (n < NN) v = ((const float4*)(x + (size_t)n * 64))[c4];
    sA[r][c4 * 4 + 0] = v.x; sA[r][c4 * 4 + 1] = v.y;
    sA[r][c4 * 4 + 2] = v.z; sA[r][c4 * 4 + 3] = v.w;
  }

  const int cg = t & 31, rg = t >> 5;
  const int j0 = cg * 4, r0 = rg * 4;
  float acc[4][4] = {};
  for (int kc = 0; kc < 4; ++kc) {
    __syncthreads();
    for (int i = t; i < 512; i += 256)
      ((float4*)sW)[i] = ((const float4*)(W1c + kc * 16 * 128))[i];
    __syncthreads();
    const int kb = kc * 16;
    for (int k = 0; k < 16; ++k) {
      float a0 = sA[r0 + 0][kb + k];
      float a1 = sA[r0 + 1][kb + k];
      float a2 = sA[r0 + 2][kb + k];
      float a3 = sA[r0 + 3][kb + k];
      float4 b = *(const float4*)&sW[k * 128 + j0];
      acc[0][0] += a0 * b.x; acc[0][1] += a0 * b.y; acc[0][2] += a0 * b.z; acc[0][3] += a0 * b.w;
      acc[1][0] += a1 * b.x; acc[1][1] += a1 * b.y; acc[1][2] += a1 * b.z; acc[1][3] += a1 * b.w;
      acc[2][0] += a2 * b.x; acc[2][1] += a2 * b.y; acc[2][2] += a2 * b.z; acc[2][3] += a2 * b.w;
      acc[3][0] += a3 * b.x; acc[3][1] += a3 * b.y; acc[3][2] += a3 * b.z; acc[3][3] += a3 * b.w;
    }
  }
  float4 bias = ((const float4*)be1)[cg];
  for (int i = 0; i < 4; ++i) {
    int n = n0 + r0 + i;
    if (n < NN) {
      float4 o = make_float4(acc[i][0] + bias.x, acc[i][1] + bias.y,
                             acc[i][2] + bias.z, acc[i][3] + bias.w);
      ((float4*)(P + (size_t)n * 128))[cg] = o;
    }
  }
}

// ---------------------------------------------------------------------------
// MFMA edge kernel, 64 edges/block, 4 waves, ONE __syncthreads.
//  h = relu(P[row] + ea @ W1f)   [GEMM1: M=64,N=128,K=64, acc init = P gather]
//  e_new = h @ We2 + be2         [GEMM2: M=64,N=64, K=128]
//  ea_out = ea + e_new ; agg[row] += e_new (atomics)
__global__ __launch_bounds__(256) void edge_kernel(
    const float* ea_in,                        // may alias ea_out
    const float* __restrict__ P,               // [N,128] fp32 (incl. be1)
    const unsigned short* __restrict__ W1fT,   // [128][64] bf16
    const unsigned short* __restrict__ We2T,   // [64][128] bf16
    const float* __restrict__ be2,             // [64]
    const int* __restrict__ row_idx,           // [E]
    float* ea_out,                             // [E,64]
    float* __restrict__ agg) {                 // [N,64]
  // strides padded to odd multiples of 16B -> 2-way (free) bank aliasing
  __shared__ unsigned short sEA[64][72];    // ea tile, bf16
  __shared__ unsigned short sW1[128][72];   // W1fT
  __shared__ unsigned short sW2[64][136];   // We2T
  __shared__ unsigned short sH[64][136];    // hidden, bf16
  __shared__ int sRow[64];

  const int t = threadIdx.x;
  const int e0 = blockIdx.x * 64;
  const int lane = t & 63;
  const int wv = t >> 6;                    // wave id 0..3
  const int l15 = lane & 15;
  const int quad = lane >> 4;               // 0..3
  const int mw = wv * 16;                   // wave's M-tile base (edges)

  if (t < 64) sRow[t] = row_idx[e0 + t];

  // stage ea fp32 -> bf16 (64 rows x 16 float4)
  for (int i = t; i < 1024; i += 256) {
    int r = i >> 4, c4 = i & 15;
    float4 v = ((const float4*)(ea_in + (size_t)(e0 + r) * 64))[c4];
    ushort4 u = make_ushort4(f2bf(v.x), f2bf(v.y), f2bf(v.z), f2bf(v.w));
    *(ushort4*)&sEA[r][c4 * 4] = u;
  }
  // stage W1fT: 128 rows x 64 bf16 = 1024 x 16B chunks (contiguous in ws)
  for (int i = t; i < 1024; i += 256) {
    *(uint4*)&sW1[i >> 3][(i & 7) * 8] = ((const uint4*)W1fT)[i];
  }
  // stage We2T: 64 rows x 128 bf16 = 1024 x 16B chunks
  for (int i = t; i < 1024; i += 256) {
    *(uint4*)&sW2[i >> 4][(i & 15) * 8] = ((const uint4*)We2T)[i];
  }
  __syncthreads();   // the only block-wide barrier

  // ---- P gather first (32 independent loads, overlap with MFMA issue)
  float pg[8][4];
  #pragma unroll
  for (int nt = 0; nt < 8; ++nt) {
    int c = nt * 16 + l15;
    #pragma unroll
    for (int r = 0; r < 4; ++r)
      pg[nt][r] = P[(size_t)sRow[mw + quad * 4 + r] * 128 + c];
  }

  // ---- GEMM1: per-wave 16x128 output tile, K=64
  bf16x8 a0 = *(const bf16x8*)&sEA[mw + l15][quad * 8];
  bf16x8 a1 = *(const bf16x8*)&sEA[mw + l15][32 + quad * 8];
  #pragma unroll
  for (int nt = 0; nt < 8; ++nt) {
    int c = nt * 16 + l15;
    f32x4 acc = {pg[nt][0], pg[nt][1], pg[nt][2], pg[nt][3]};
    bf16x8 b0 = *(const bf16x8*)&sW1[c][quad * 8];
    bf16x8 b1 = *(const bf16x8*)&sW1[c][32 + quad * 8];
    acc = __builtin_amdgcn_mfma_f32_16x16x32_bf16(a0, b0, acc, 0, 0, 0);
    acc = __builtin_amdgcn_mfma_f32_16x16x32_bf16(a1, b1, acc, 0, 0, 0);
    // relu -> sH (own wave's rows only; no cross-wave dependency)
    #pragma unroll
    for (int r = 0; r < 4; ++r)
      sH[mw + quad * 4 + r][c] = f2bf(fmaxf(acc[r], 0.f));
  }

  // ---- GEMM2: per-wave 16x64 output tile, K=128
  bf16x8 ha[4];
  #pragma unroll
  for (int kk = 0; kk < 4; ++kk)
    ha[kk] = *(const bf16x8*)&sH[mw + l15][kk * 32 + quad * 8];
  #pragma unroll
  for (int nt = 0; nt < 4; ++nt) {
    int c = nt * 16 + l15;
    f32x4 acc = {0.f, 0.f, 0.f, 0.f};
    #pragma unroll
    for (int kk = 0; kk < 4; ++kk) {
      bf16x8 b = *(const bf16x8*)&sW2[c][kk * 32 + quad * 8];
      acc = __builtin_amdgcn_mfma_f32_16x16x32_bf16(ha[kk], b, acc, 0, 0, 0);
    }
    float bias = be2[c];
    #pragma unroll
    for (int r = 0; r < 4; ++r) {
      int m = mw + quad * 4 + r;
      float v = acc[r] + bias;
      size_t off = (size_t)(e0 + m) * 64 + c;
      ea_out[off] = ea_in[off] + v;   // reread (L1/L2-hot); ok when aliased
      atomicAdd(&agg[(size_t)sRow[m] * 64 + c], v);
    }
  }
}

// ---------------------------------------------------------------------------
// x_out = x + (relu([x | agg/denom] @ Wn1 + bn1) @ Wn2 + bn2)   (fp32)
__global__ __launch_bounds__(256) void node_kernel(
    const float* x,
    const float* __restrict__ agg,
    const float* __restrict__ cnt,
    const float* __restrict__ Wn1,
    const float* __restrict__ bn1,
    const float* __restrict__ Wn2,
    const float* __restrict__ bn2,
    float* x_out) {
  __shared__ float sA[32][132];
  __shared__ float sH[32][132];
  __shared__ float sW[16 * 128];
  const int t = threadIdx.x;
  const int n0 = blockIdx.x * 32;

  for (int i = t; i < 1024; i += 256) {
    int r = i >> 5, c4 = i & 31;
    int n = n0 + r;
    float4 v = make_float4(0.f, 0.f, 0.f, 0.f);
    if (n < NN) {
      if (c4 < 16) {
        v = ((const float4*)(x + (size_t)n * 64))[c4];
      } else {
        v = ((const float4*)(agg + (size_t)n * 64))[c4 - 16];
        float inv = 1.0f / fmaxf(cnt[n], 1.0f);
        v.x *= inv; v.y *= inv; v.z *= inv; v.w *= inv;
      }
    }
    sA[r][c4 * 4 + 0] = v.x; sA[r][c4 * 4 + 1] = v.y;
    sA[r][c4 * 4 + 2] = v.z; sA[r][c4 * 4 + 3] = v.w;
  }

  const int cg = t & 31, rg = t >> 5;
  const int j0 = cg * 4, r0 = rg * 4;
  float acc[4][4] = {};
  for (int kc = 0; kc < 8; ++kc) {
    __syncthreads();
    for (int i = t; i < 512; i += 256)
      ((float4*)sW)[i] = ((const float4*)(Wn1 + kc * 16 * 128))[i];
    __syncthreads();
    const int kb = kc * 16;
    for (int k = 0; k < 16; ++k) {
      float a0 = sA[r0 + 0][kb + k];
      float a1 = sA[r0 + 1][kb + k];
      float a2 = sA[r0 + 2][kb + k];
      float a3 = sA[r0 + 3][kb + k];
      float4 b = *(const float4*)&sW[k * 128 + j0];
      acc[0][0] += a0 * b.x; acc[0][1] += a0 * b.y; acc[0][2] += a0 * b.z; acc[0][3] += a0 * b.w;
      acc[1][0] += a1 * b.x; acc[1][1] += a1 * b.y; acc[1][2] += a1 * b.z; acc[1][3] += a1 * b.w;
      acc[2][0] += a2 * b.x; acc[2][1] += a2 * b.y; acc[2][2] += a2 * b.z; acc[2][3] += a2 * b.w;
      acc[3][0] += a3 * b.x; acc[3][1] += a3 * b.y; acc[3][2] += a3 * b.z; acc[3][3] += a3 * b.w;
    }
  }
  float4 b1 = ((const float4*)bn1)[cg];
  for (int i = 0; i < 4; ++i) {
    sH[r0 + i][j0 + 0] = fmaxf(acc[i][0] + b1.x, 0.f);
    sH[r0 + i][j0 + 1] = fmaxf(acc[i][1] + b1.y, 0.f);
    sH[r0 + i][j0 + 2] = fmaxf(acc[i][2] + b1.z, 0.f);
    sH[r0 + i][j0 + 3] = fmaxf(acc[i][3] + b1.w, 0.f);
  }

  const int cg2 = t & 15, rg2 = t >> 4;
  const int j2 = cg2 * 4, r2 = rg2 * 2;
  float acc2[2][4] = {};
  for (int kc = 0; kc < 4; ++kc) {
    __syncthreads();
    for (int i = t; i < 512; i += 256)
      ((float4*)sW)[i] = ((const float4*)(Wn2 + kc * 32 * 64))[i];
    __syncthreads();
    const int kb = kc * 32;
    for (int k = 0; k < 32; ++k) {
      float a0 = sH[r2 + 0][kb + k];
      float a1 = sH[r2 + 1][kb + k];
      float4 b = *(const float4*)&sW[k * 64 + j2];
      acc2[0][0] += a0 * b.x; acc2[0][1] += a0 * b.y; acc2[0][2] += a0 * b.z; acc2[0][3] += a0 * b.w;
      acc2[1][0] += a1 * b.x; acc2[1][1] += a1 * b.y; acc2[1][2] += a1 * b.z; acc2[1][3] += a1 * b.w;
    }
  }
  float4 b2 = ((const float4*)bn2)[cg2];
  for (int i = 0; i < 2; ++i) {
    int n = n0 + r2 + i;
    if (n < NN) {
      float4 o;
      o.x = sA[r2 + i][j2 + 0] + acc2[i][0] + b2.x;
      o.y = sA[r2 + i][j2 + 1] + acc2[i][1] + b2.y;
      o.z = sA[r2 + i][j2 + 2] + acc2[i][2] + b2.z;
      o.w = sA[r2 + i][j2 + 3] + acc2[i][3] + b2.w;
      ((float4*)(x_out + (size_t)n * 64))[cg2] = o;
    }
  }
}

// ---------------------------------------------------------------------------
extern "C" void kernel_launch(void* const* d_in, const int* in_sizes, int n_in,
                              void* d_out, int out_size, void* d_ws, size_t ws_size,
                              hipStream_t stream) {
  const float* x   = (const float*)d_in[0];
  const float* ea  = (const float*)d_in[1];
  const float* We1 = (const float*)d_in[2];
  const float* be1 = (const float*)d_in[3];
  const float* We2 = (const float*)d_in[4];
  const float* be2 = (const float*)d_in[5];
  const float* Wn1 = (const float*)d_in[6];
  const float* bn1 = (const float*)d_in[7];
  const float* Wn2 = (const float*)d_in[8];
  const float* bn2 = (const float*)d_in[9];
  const int*   ei  = (const int*)d_in[10];   // row = ei[0..E)

  float* x_out  = (float*)d_out;                       // [N,64]
  float* ea_out = (float*)d_out + (size_t)NN * 64;     // [E,64]

  // ws (floats): cnt[50048] | agg[N*64] | P[N*128] | W1c[8192] | bf16 weights
  float* cnt = (float*)d_ws;
  float* agg = cnt + 50048;
  float* P   = agg + (size_t)NN * 64;
  float* W1c = P + (size_t)NN * 128;
  unsigned short* W1fT = (unsigned short*)(W1c + 8192);   // [128][64] bf16
  unsigned short* We2T = W1fT + 8192;                      // [64][128] bf16

  hipMemsetAsync(cnt, 0, NN * sizeof(float), stream);
  hipMemsetAsync(agg, 0, (size_t)NN * 64 * sizeof(float), stream);
  count_kernel<<<(NE + 255) / 256, 256, 0, stream>>>(ei, cnt);
  prep_w1c<<<32, 256, 0, stream>>>(We1, W1c);
  prep_edge_w<<<64, 256, 0, stream>>>(We1, We2, W1fT, We2T);

  const int nbN = (NN + 31) / 32;   // 1563
  const int nbE = NE / 64;          // 12500

  // iter 1
  node_pre<<<nbN, 256, 0, stream>>>(x, W1c, be1, P);
  edge_kernel<<<nbE, 256, 0, stream>>>(ea, P, W1fT, We2T, be2, ei, ea_out, agg);
  node_kernel<<<nbN, 256, 0, stream>>>(x, agg, cnt, Wn1, bn1, Wn2, bn2, x_out);

  // iter 2 (in-place on d_out)
  hipMemsetAsync(agg, 0, (size_t)NN * 64 * sizeof(float), stream);
  node_pre<<<nbN, 256, 0, stream>>>(x_out, W1c, be1, P);
  edge_kernel<<<nbE, 256, 0, stream>>>(ea_out, P, W1fT, We2T, be2, ei, ea_out, agg);
  node_kernel<<<nbN, 256, 0, stream>>>(x_out, agg, cnt, Wn1, bn1, Wn2, bn2, x_out);
}